// Round 1
// baseline (1619.797 us; speedup 1.0000x reference)
//
#include <hip/hip_runtime.h>

#define HID   24
#define T_LEN 4096
#define BATCH 1024
#define NB    2                 // batches per block
#define LPB   3                 // layers
#define TPB   (NB * LPB * HID)  // 144 threads
#define TC    512               // x chunk length (power of 2)

__global__ __launch_bounds__(TPB) void rnn_scan_kernel(
    const float* __restrict__ x,     // [B, T]
    const float* __restrict__ h_in,  // [3, B, 24]
    const float* __restrict__ Wih0, const float* __restrict__ bih0,
    const float* __restrict__ Whh0, const float* __restrict__ bhh0,
    const float* __restrict__ Wih1, const float* __restrict__ bih1,
    const float* __restrict__ Whh1, const float* __restrict__ bhh1,
    const float* __restrict__ Wih2, const float* __restrict__ bih2,
    const float* __restrict__ Whh2, const float* __restrict__ bhh2,
    const float* __restrict__ W1,   const float* __restrict__ b1,
    const float* __restrict__ W2,   const float* __restrict__ b2,
    float* __restrict__ out)         // [1024 (y)] ++ [3*1024*24 (h_final)]
{
    // hbuf[parity][b_local][slot][k]; slot 0 = broadcast x(t), slots 1..3 = h of layers 0..2
    __shared__ __align__(16) float hbuf[2][NB][4][HID];
    __shared__ __align__(16) float xs[NB][TC];
    __shared__ float mbuf[NB][HID];

    const int tid = threadIdx.x;
    const int j   = tid % HID;
    const int ul  = tid / HID;       // 0 .. NB*3-1
    const int l   = ul % LPB;        // layer
    const int bl  = ul / LPB;        // local batch
    const int bg  = blockIdx.x * NB + bl;

    // ---- per-thread weights into registers: w[0..23] = ih row, w[24..47] = hh row ----
    float w[2 * HID];
    float bias;
    {
        const float* wihrow = Whh0;  // placeholder (unused for l==0)
        const float* whhrow;
        if (l == 0)      { whhrow = Whh0 + j * HID; bias = bih0[j] + bhh0[j]; }
        else if (l == 1) { wihrow = Wih1 + j * HID; whhrow = Whh1 + j * HID; bias = bih1[j] + bhh1[j]; }
        else             { wihrow = Wih2 + j * HID; whhrow = Whh2 + j * HID; bias = bih2[j] + bhh2[j]; }
        const float wx0 = Wih0[j];   // layer 0: scalar input weight
        #pragma unroll
        for (int k = 0; k < HID; ++k) {
            w[k]       = (l == 0) ? ((k == 0) ? wx0 : 0.0f) : wihrow[k];
            w[HID + k] = whhrow[k];
        }
    }

    float cur = h_in[(l * BATCH + bg) * HID + j];  // running h for (l, bg, j)

    // ---- seed parity-0 buffer + first x chunk ----
    hbuf[0][bl][l + 1][j] = cur;
    if (l == 0) hbuf[0][bl][0][j] = x[(size_t)bg * T_LEN];  // x(0) broadcast
    for (int idx = tid; idx < NB * TC / 4; idx += TPB) {
        const int bb = idx / (TC / 4), o = idx % (TC / 4);
        ((float4*)&xs[bb][0])[o] =
            ((const float4*)(x + (size_t)(blockIdx.x * NB + bb) * T_LEN))[o];
    }
    __syncthreads();

    // ---- pipelined scan: tick u, layer l processes t = u - l ----
    int p = 0;
    const int U = T_LEN + LPB - 1;   // 4098
    for (int u = 0; u < U; ++u) {
        // reload x chunk so that x(u+1) is available this tick
        if (((u + 1) & (TC - 1)) == 0 && (u + 1) < T_LEN) {
            const int c0 = u + 1;
            for (int idx = tid; idx < NB * TC / 4; idx += TPB) {
                const int bb = idx / (TC / 4), o = idx % (TC / 4);
                ((float4*)&xs[bb][0])[o] =
                    ((const float4*)(x + (size_t)(blockIdx.x * NB + bb) * T_LEN + c0))[o];
            }
            __syncthreads();
        }

        // 48 contiguous inputs: slots l (input-from-below) and l+1 (own h)
        const float* rb = &hbuf[p][bl][l][0];
        float a0 = 0.f, a1 = 0.f, a2 = 0.f, a3 = 0.f;
        #pragma unroll
        for (int k = 0; k < 2 * HID; k += 16) {
            const float4 v0 = *(const float4*)(rb + k);
            const float4 v1 = *(const float4*)(rb + k + 4);
            const float4 v2 = *(const float4*)(rb + k + 8);
            const float4 v3 = *(const float4*)(rb + k + 12);
            a0 = fmaf(w[k + 0],  v0.x, a0); a0 = fmaf(w[k + 1],  v0.y, a0);
            a0 = fmaf(w[k + 2],  v0.z, a0); a0 = fmaf(w[k + 3],  v0.w, a0);
            a1 = fmaf(w[k + 4],  v1.x, a1); a1 = fmaf(w[k + 5],  v1.y, a1);
            a1 = fmaf(w[k + 6],  v1.z, a1); a1 = fmaf(w[k + 7],  v1.w, a1);
            a2 = fmaf(w[k + 8],  v2.x, a2); a2 = fmaf(w[k + 9],  v2.y, a2);
            a2 = fmaf(w[k + 10], v2.z, a2); a2 = fmaf(w[k + 11], v2.w, a2);
            a3 = fmaf(w[k + 12], v3.x, a3); a3 = fmaf(w[k + 13], v3.y, a3);
            a3 = fmaf(w[k + 14], v3.z, a3); a3 = fmaf(w[k + 15], v3.w, a3);
        }
        const float acc = bias + ((a0 + a1) + (a2 + a3));

        const int t = u - l;
        const bool active = (t >= 0) && (t < T_LEN);
        const float nv = fmaxf(acc, 0.0f);
        cur = active ? nv : cur;

        hbuf[p ^ 1][bl][l + 1][j] = cur;
        if (l == 0) {
            const float xn = ((u + 1) < T_LEN) ? xs[bl][(u + 1) & (TC - 1)] : 0.0f;
            hbuf[p ^ 1][bl][0][j] = xn;   // broadcast x(u+1) for next tick
        }
        __syncthreads();
        p ^= 1;
    }

    // ---- h_final straight from registers ----
    out[BATCH + (l * BATCH + bg) * HID + j] = cur;

    // ---- MLP head on h2(T-1) (in hbuf[p] slot 3) ----
    if (l == 2) {
        const float* h2f = &hbuf[p][bl][3][0];
        float a = b1[j];
        #pragma unroll
        for (int k = 0; k < HID; ++k) a = fmaf(W1[j * HID + k], h2f[k], a);
        mbuf[bl][j] = fmaxf(a, 0.0f);
    }
    __syncthreads();
    if (l == 2 && j == 0) {
        float a = b2[0];
        #pragma unroll
        for (int k = 0; k < HID; ++k) a = fmaf(W2[k], mbuf[bl][k], a);
        out[bg] = fmaxf(a, 0.0f);
    }
}

extern "C" void kernel_launch(void* const* d_in, const int* in_sizes, int n_in,
                              void* d_out, int out_size, void* d_ws, size_t ws_size,
                              hipStream_t stream) {
    const float* x    = (const float*)d_in[0];
    const float* h_in = (const float*)d_in[1];
    const float* Wih0 = (const float*)d_in[2];
    const float* bih0 = (const float*)d_in[3];
    const float* Whh0 = (const float*)d_in[4];
    const float* bhh0 = (const float*)d_in[5];
    const float* Wih1 = (const float*)d_in[6];
    const float* bih1 = (const float*)d_in[7];
    const float* Whh1 = (const float*)d_in[8];
    const float* bhh1 = (const float*)d_in[9];
    const float* Wih2 = (const float*)d_in[10];
    const float* bih2 = (const float*)d_in[11];
    const float* Whh2 = (const float*)d_in[12];
    const float* bhh2 = (const float*)d_in[13];
    const float* W1   = (const float*)d_in[14];
    const float* b1   = (const float*)d_in[15];
    const float* W2   = (const float*)d_in[16];
    const float* b2   = (const float*)d_in[17];
    float* out = (float*)d_out;

    dim3 grid(BATCH / NB);   // 512 blocks
    dim3 block(TPB);         // 144 threads
    hipLaunchKernelGGL(rnn_scan_kernel, grid, block, 0, stream,
                       x, h_in, Wih0, bih0, Whh0, bhh0,
                       Wih1, bih1, Whh1, bhh1, Wih2, bih2, Whh2, bhh2,
                       W1, b1, W2, b2, out);
}

// Round 2
// 1280.434 us; speedup vs baseline: 1.2650x; 1.2650x over previous
//
#include <hip/hip_runtime.h>

#define HID   24
#define T_LEN 4096
#define BATCH 1024
#define NB    2                 // batches per block
#define TPB   (NB * 3 * HID)    // 144 threads
#define TC    512               // x chunk length (power of 2)

__device__ __forceinline__ float dot4(const float4 a, const float4 b, float acc) {
    acc = fmaf(a.x, b.x, acc);
    acc = fmaf(a.y, b.y, acc);
    acc = fmaf(a.z, b.z, acc);
    acc = fmaf(a.w, b.w, acc);
    return acc;
}

__global__ __launch_bounds__(TPB, 1) void rnn_scan_kernel(
    const float* __restrict__ x,     // [B, T]
    const float* __restrict__ h_in,  // [3, B, 24]
    const float* __restrict__ Wih0, const float* __restrict__ bih0,
    const float* __restrict__ Whh0, const float* __restrict__ bhh0,
    const float* __restrict__ Wih1, const float* __restrict__ bih1,
    const float* __restrict__ Whh1, const float* __restrict__ bhh1,
    const float* __restrict__ Wih2, const float* __restrict__ bih2,
    const float* __restrict__ Whh2, const float* __restrict__ bhh2,
    const float* __restrict__ W1,   const float* __restrict__ b1,
    const float* __restrict__ W2,   const float* __restrict__ b2,
    float* __restrict__ out)         // [1024 (y)] ++ [3*1024*24 (h_final)]
{
    // hbuf[parity][b_local][slot][k]; slot 0 = broadcast x(t), slots 1..3 = h of layers 0..2
    __shared__ __align__(16) float hbuf[2][NB][4][HID];
    __shared__ __align__(16) float xs[NB][TC];
    __shared__ float mbuf[NB][HID];

    const int tid = threadIdx.x;
    const int j   = tid % HID;
    const int ul  = tid / HID;       // 0 .. NB*3-1
    const int l   = ul % 3;          // layer
    const int bl  = ul / 3;          // local batch
    const int bg  = blockIdx.x * NB + bl;

    // ---- weights in NAMED float4 registers (no indexable arrays -> no scratch) ----
    // wi0..wi5: input-from-below row (24)   wh0..wh5: own-h row (24)
    float4 wi0, wi1, wi2, wi3, wi4, wi5;
    float4 wh0, wh1, wh2, wh3, wh4, wh5;
    float bias;
    {
        const float* hhrow = ((l == 0) ? Whh0 : (l == 1) ? Whh1 : Whh2) + j * HID;
        const float4* hh4 = (const float4*)hhrow;   // j*96B: 16B-aligned
        wh0 = hh4[0]; wh1 = hh4[1]; wh2 = hh4[2];
        wh3 = hh4[3]; wh4 = hh4[4]; wh5 = hh4[5];
        if (l == 0) {
            wi0 = make_float4(Wih0[j], 0.f, 0.f, 0.f);
            wi1 = wi2 = wi3 = wi4 = wi5 = make_float4(0.f, 0.f, 0.f, 0.f);
            bias = bih0[j] + bhh0[j];
        } else if (l == 1) {
            const float4* ih4 = (const float4*)(Wih1 + j * HID);
            wi0 = ih4[0]; wi1 = ih4[1]; wi2 = ih4[2];
            wi3 = ih4[3]; wi4 = ih4[4]; wi5 = ih4[5];
            bias = bih1[j] + bhh1[j];
        } else {
            const float4* ih4 = (const float4*)(Wih2 + j * HID);
            wi0 = ih4[0]; wi1 = ih4[1]; wi2 = ih4[2];
            wi3 = ih4[3]; wi4 = ih4[4]; wi5 = ih4[5];
            bias = bih2[j] + bhh2[j];
        }
    }

    float cur = h_in[(l * BATCH + bg) * HID + j];  // running h for (l, bg, j)

    // ---- seed parity-0 buffer + first x chunk ----
    hbuf[0][bl][l + 1][j] = cur;
    if (l == 0) hbuf[0][bl][0][j] = x[(size_t)bg * T_LEN];  // x(0) broadcast
    for (int idx = tid; idx < NB * TC / 4; idx += TPB) {
        const int bb = idx / (TC / 4), o = idx % (TC / 4);
        ((float4*)&xs[bb][0])[o] =
            ((const float4*)(x + (size_t)(blockIdx.x * NB + bb) * T_LEN))[o];
    }
    __syncthreads();

    // one tick: read hbuf[RP], write hbuf[WP]; all operands/weights in registers
#define TICK(RP, WP, UU)                                                          \
    do {                                                                          \
        const float4* rb = (const float4*)&hbuf[RP][bl][l][0];                    \
        const float4 v0 = rb[0], v1 = rb[1], v2 = rb[2];                          \
        const float4 v3 = rb[3], v4 = rb[4], v5 = rb[5];                          \
        const float4 v6 = rb[6], v7 = rb[7], v8 = rb[8];                          \
        const float4 v9 = rb[9], v10 = rb[10], v11 = rb[11];                      \
        float a0 = dot4(wi0, v0, 0.f), a1 = dot4(wi1, v1, 0.f);                   \
        float a2 = dot4(wi2, v2, 0.f), a3 = dot4(wi3, v3, 0.f);                   \
        a0 = dot4(wi4, v4, a0);  a1 = dot4(wi5, v5, a1);                          \
        a2 = dot4(wh0, v6, a2);  a3 = dot4(wh1, v7, a3);                          \
        a0 = dot4(wh2, v8, a0);  a1 = dot4(wh3, v9, a1);                          \
        a2 = dot4(wh4, v10, a2); a3 = dot4(wh5, v11, a3);                         \
        const float acc = bias + ((a0 + a1) + (a2 + a3));                         \
        const int t = (UU) - l;                                                   \
        const float nv = fmaxf(acc, 0.f);                                         \
        cur = (t >= 0 && t < T_LEN) ? nv : cur;                                   \
        hbuf[WP][bl][l + 1][j] = cur;                                             \
        if (l == 0) {                                                             \
            const float xn = (((UU) + 1) < T_LEN) ? xs[bl][((UU) + 1) & (TC - 1)] \
                                                  : 0.f;                          \
            hbuf[WP][bl][0][j] = xn;                                              \
        }                                                                         \
        __syncthreads();                                                          \
    } while (0)

    // ---- pipelined scan: tick u, layer l processes t = u - l; unroll x2 ----
    const int U = T_LEN + 2;   // 4098 (even)
    for (int u = 0; u < U; u += 2) {
        TICK(0, 1, u);
        // tick u+1 will read x(u+2) at its end; reload chunk if crossing boundary
        if (((u + 2) & (TC - 1)) == 0 && (u + 2) < T_LEN) {
            const int c0 = u + 2;
            for (int idx = tid; idx < NB * TC / 4; idx += TPB) {
                const int bb = idx / (TC / 4), o = idx % (TC / 4);
                ((float4*)&xs[bb][0])[o] =
                    ((const float4*)(x + (size_t)(blockIdx.x * NB + bb) * T_LEN + c0))[o];
            }
            __syncthreads();
        }
        TICK(1, 0, u + 1);
    }
#undef TICK

    // ---- h_final straight from registers ----
    out[BATCH + (l * BATCH + bg) * HID + j] = cur;

    // ---- MLP head on h2(T-1) (U even -> final state is in hbuf[0] slot 3) ----
    if (l == 2) {
        const float4* w1r = (const float4*)(W1 + j * HID);   // 96B-aligned rows
        const float4* hv  = (const float4*)&hbuf[0][bl][3][0];
        float a = b1[j];
        a = dot4(w1r[0], hv[0], a); a = dot4(w1r[1], hv[1], a);
        a = dot4(w1r[2], hv[2], a); a = dot4(w1r[3], hv[3], a);
        a = dot4(w1r[4], hv[4], a); a = dot4(w1r[5], hv[5], a);
        mbuf[bl][j] = fmaxf(a, 0.f);
    }
    __syncthreads();
    if (l == 2 && j == 0) {
        float a = b2[0];
        #pragma unroll
        for (int k = 0; k < HID; ++k) a = fmaf(W2[k], mbuf[bl][k], a);
        out[bg] = fmaxf(a, 0.f);
    }
}

extern "C" void kernel_launch(void* const* d_in, const int* in_sizes, int n_in,
                              void* d_out, int out_size, void* d_ws, size_t ws_size,
                              hipStream_t stream) {
    const float* x    = (const float*)d_in[0];
    const float* h_in = (const float*)d_in[1];
    const float* Wih0 = (const float*)d_in[2];
    const float* bih0 = (const float*)d_in[3];
    const float* Whh0 = (const float*)d_in[4];
    const float* bhh0 = (const float*)d_in[5];
    const float* Wih1 = (const float*)d_in[6];
    const float* bih1 = (const float*)d_in[7];
    const float* Whh1 = (const float*)d_in[8];
    const float* bhh1 = (const float*)d_in[9];
    const float* Wih2 = (const float*)d_in[10];
    const float* bih2 = (const float*)d_in[11];
    const float* Whh2 = (const float*)d_in[12];
    const float* bhh2 = (const float*)d_in[13];
    const float* W1   = (const float*)d_in[14];
    const float* b1   = (const float*)d_in[15];
    const float* W2   = (const float*)d_in[16];
    const float* b2   = (const float*)d_in[17];
    float* out = (float*)d_out;

    dim3 grid(BATCH / NB);   // 512 blocks -> 2 blocks/CU for barrier-latency overlap
    dim3 block(TPB);         // 144 threads
    hipLaunchKernelGGL(rnn_scan_kernel, grid, block, 0, stream,
                       x, h_in, Wih0, bih0, Whh0, bhh0,
                       Wih1, bih1, Whh1, bhh1, Wih2, bih2, Whh2, bhh2,
                       W1, b1, W2, b2, out);
}

// Round 3
// 1145.522 us; speedup vs baseline: 1.4140x; 1.1178x over previous
//
#include <hip/hip_runtime.h>

#define HID   24
#define T_LEN 4096
#define BATCH 1024
#define NB    2                  // batches per block (one per 32-lane half)
#define K     8                  // timesteps per chunk (pipeline skew per layer)
#define NC    (T_LEN / K)        // 512 active chunks per layer
#define CTOT  (NC + 2)           // 514 total ticks (3-layer skew)
#define XC    512                // x staging chunk (elements)
#define TPB   192                // 3 full waves: wave w == layer w

__device__ __forceinline__ float dot4(const float4 a, const float4 b, float acc) {
    acc = fmaf(a.x, b.x, acc);
    acc = fmaf(a.y, b.y, acc);
    acc = fmaf(a.z, b.z, acc);
    acc = fmaf(a.w, b.w, acc);
    return acc;
}

__device__ __forceinline__ float dot24(const float* p,
                                       const float4 w0, const float4 w1, const float4 w2,
                                       const float4 w3, const float4 w4, const float4 w5) {
    const float4* r = (const float4*)p;
    float a0 = dot4(w0, r[0], 0.f);
    float a1 = dot4(w1, r[1], 0.f);
    float a2 = dot4(w2, r[2], 0.f);
    float a3 = dot4(w3, r[3], 0.f);
    a0 = dot4(w4, r[4], a0);
    a1 = dot4(w5, r[5], a1);
    return (a0 + a1) + (a2 + a3);
}

__global__ __launch_bounds__(TPB, 2) void rnn_scan_kernel(
    const float* __restrict__ x,     // [B, T]
    const float* __restrict__ h_in,  // [3, B, 24]
    const float* __restrict__ Wih0, const float* __restrict__ bih0,
    const float* __restrict__ Whh0, const float* __restrict__ bhh0,
    const float* __restrict__ Wih1, const float* __restrict__ bih1,
    const float* __restrict__ Whh1, const float* __restrict__ bhh1,
    const float* __restrict__ Wih2, const float* __restrict__ bih2,
    const float* __restrict__ Whh2, const float* __restrict__ bhh2,
    const float* __restrict__ W1,   const float* __restrict__ b1,
    const float* __restrict__ W2,   const float* __restrict__ b2,
    float* __restrict__ out)         // [1024 (y)] ++ [3*1024*24 (h_final)]
{
    // hbuf[parity][bl][layer][step][j]; inner dim 24 floats = 96B (16B aligned rows)
    __shared__ __align__(16) float hbuf[2][NB][3][K][HID];
    __shared__ __align__(16) float xs[NB][XC];
    __shared__ float mbuf[NB][HID];

    const int tid  = threadIdx.x;
    const int l    = tid >> 6;        // wave id == layer
    const int lane = tid & 63;
    const int bl   = lane >> 5;       // batch half
    const int jj   = lane & 31;
    const bool act = (jj < HID);
    const int j    = act ? jj : 0;    // clamped for safe addressing
    const int bg   = blockIdx.x * NB + bl;

    // ---- weights in named float4 registers ----
    float4 wi0, wi1, wi2, wi3, wi4, wi5;   // input-from-below row (layers 1,2)
    float4 wh0, wh1, wh2, wh3, wh4, wh5;   // own-h row
    float wx0 = 0.f, bias;
    {
        const float* hhrow = ((l == 0) ? Whh0 : (l == 1) ? Whh1 : Whh2) + j * HID;
        const float4* hh4 = (const float4*)hhrow;
        wh0 = hh4[0]; wh1 = hh4[1]; wh2 = hh4[2];
        wh3 = hh4[3]; wh4 = hh4[4]; wh5 = hh4[5];
        if (l == 0) {
            wx0 = Wih0[j];
            bias = bih0[j] + bhh0[j];
            wi0 = wi1 = wi2 = wi3 = wi4 = wi5 = make_float4(0.f, 0.f, 0.f, 0.f);
        } else {
            const float4* ih4 = (const float4*)(((l == 1) ? Wih1 : Wih2) + j * HID);
            wi0 = ih4[0]; wi1 = ih4[1]; wi2 = ih4[2];
            wi3 = ih4[3]; wi4 = ih4[4]; wi5 = ih4[5];
            bias = (l == 1) ? (bih1[j] + bhh1[j]) : (bih2[j] + bhh2[j]);
        }
    }

    // ---- initial state; seed BOTH parities' [l][K-1] rows ----
    float cur = act ? h_in[(l * BATCH + bg) * HID + j] : 0.f;
    if (act) {
        hbuf[0][bl][l][K - 1][j] = cur;
        hbuf[1][bl][l][K - 1][j] = cur;
    }
    // ---- stage first x region ----
    for (int idx = tid; idx < NB * XC / 4; idx += TPB) {
        const int bb = idx / (XC / 4), o = idx % (XC / 4);
        ((float4*)&xs[bb][0])[o] =
            ((const float4*)(x + (size_t)(blockIdx.x * NB + bb) * T_LEN))[o];
    }
    __syncthreads();

    // ---- chunked, layer-skewed scan: chunk c, layer l handles t in [(c-l)*K, +K) ----
    for (int c = 0; c < CTOT; ++c) {
        const int wp = c & 1, rp = wp ^ 1;
        if (c >= l && c < l + NC) {
            const int t0   = (c - l) * K;
            const int xoff = t0 & (XC - 1);
            if (l == 0) {
                #pragma unroll
                for (int s = 0; s < K; ++s) {
                    const float* own = (s == 0) ? &hbuf[rp][bl][0][K - 1][0]
                                                : &hbuf[wp][bl][0][s - 1][0];
                    const float xv = xs[bl][xoff + s];
                    float acc = bias + wx0 * xv
                              + dot24(own, wh0, wh1, wh2, wh3, wh4, wh5);
                    cur = fmaxf(acc, 0.f);
                    if (act) hbuf[wp][bl][0][s][j] = cur;
                }
            } else {
                #pragma unroll
                for (int s = 0; s < K; ++s) {
                    const float* inp = &hbuf[rp][bl][l - 1][s][0];
                    const float* own = (s == 0) ? &hbuf[rp][bl][l][K - 1][0]
                                                : &hbuf[wp][bl][l][s - 1][0];
                    float acc = bias
                              + dot24(inp, wi0, wi1, wi2, wi3, wi4, wi5)
                              + dot24(own, wh0, wh1, wh2, wh3, wh4, wh5);
                    cur = fmaxf(acc, 0.f);
                    if (act) hbuf[wp][bl][l][s][j] = cur;
                }
            }
        }
        __syncthreads();
        // stage next x region if the next chunk crosses an XC boundary
        const int cn = c + 1;
        if (cn < NC && ((cn * K) & (XC - 1)) == 0) {
            for (int idx = tid; idx < NB * XC / 4; idx += TPB) {
                const int bb = idx / (XC / 4), o = idx % (XC / 4);
                ((float4*)&xs[bb][0])[o] =
                    ((const float4*)(x + (size_t)(blockIdx.x * NB + bb) * T_LEN + cn * K))[o];
            }
            __syncthreads();
        }
    }

    // ---- h_final from registers ----
    if (act) out[BATCH + (l * BATCH + bg) * HID + j] = cur;

    // ---- MLP head on h2(T-1): hbuf[(CTOT-1)&1][bl][2][K-1] ----
    if (l == 2 && act) {
        const float* h2f = &hbuf[(CTOT - 1) & 1][bl][2][K - 1][0];
        const float4* w1r = (const float4*)(W1 + j * HID);
        float a = b1[j] + dot24(h2f, w1r[0], w1r[1], w1r[2], w1r[3], w1r[4], w1r[5]);
        mbuf[bl][j] = fmaxf(a, 0.f);
    }
    __syncthreads();
    if (l == 2 && jj == 0) {
        float a = b2[0];
        #pragma unroll
        for (int k = 0; k < HID; ++k) a = fmaf(W2[k], mbuf[bl][k], a);
        out[bg] = fmaxf(a, 0.f);
    }
}

extern "C" void kernel_launch(void* const* d_in, const int* in_sizes, int n_in,
                              void* d_out, int out_size, void* d_ws, size_t ws_size,
                              hipStream_t stream) {
    const float* x    = (const float*)d_in[0];
    const float* h_in = (const float*)d_in[1];
    const float* Wih0 = (const float*)d_in[2];
    const float* bih0 = (const float*)d_in[3];
    const float* Whh0 = (const float*)d_in[4];
    const float* bhh0 = (const float*)d_in[5];
    const float* Wih1 = (const float*)d_in[6];
    const float* bih1 = (const float*)d_in[7];
    const float* Whh1 = (const float*)d_in[8];
    const float* bhh1 = (const float*)d_in[9];
    const float* Wih2 = (const float*)d_in[10];
    const float* bih2 = (const float*)d_in[11];
    const float* Whh2 = (const float*)d_in[12];
    const float* bhh2 = (const float*)d_in[13];
    const float* W1   = (const float*)d_in[14];
    const float* b1   = (const float*)d_in[15];
    const float* W2   = (const float*)d_in[16];
    const float* b2   = (const float*)d_in[17];
    float* out = (float*)d_out;

    dim3 grid(BATCH / NB);   // 512 blocks -> 2 blocks/CU
    dim3 block(TPB);         // 3 full waves (wave == layer)
    hipLaunchKernelGGL(rnn_scan_kernel, grid, block, 0, stream,
                       x, h_in, Wih0, bih0, Whh0, bhh0,
                       Wih1, bih1, Whh1, bhh1, Wih2, bih2, Whh2, bhh2,
                       W1, b1, W2, b2, out);
}